// Round 4
// baseline (1305.918 us; speedup 1.0000x reference)
//
#include <hip/hip_runtime.h>
#include <hip/hip_bf16.h>

// TransformerSpatialAttention on MI355X (gfx950)
// B=8, C=192, H=W=256, WS=8 -> 8192 windows x 64 tokens x 192 ch, NH=8, HD=24.
//
// Algebraic reduction (carried over): out = sigmoid(xa . wbar + bbar);
// V never stored, projection GEMM never run.
//
// Round-4: round 3 hit 1 block/CU despite 128-VGPR report -- accumulators
// overflowed to AGPRs (unified file, arch cap 128) -> ~144 total/wave -> only
// 12 waves/CU -> second 8-wave workgroup can't fit. Fix = cut real demand:
//  - un-padded q/k LDS (24 ch/head, stride 200; lg==3 fragment = zeros) ->
//    xn stays resident (77 KB total, no alias, no B2 barrier, no pad re-zero)
//  - wave owns fixed row-tile mi=w&3, j-half jh=w>>2 (18 tiles, balanced):
//    af[4][6] (96 regs) -> af[6] (24); accumulator = one floatx4
//  - attention computed per row-block i: sc[4][4] (64) -> sc[4] (16)
// Peak live ~70-90 regs -> 2 blocks/CU at 128-VGPR class.

typedef __attribute__((ext_vector_type(4))) float floatx4;
typedef __attribute__((ext_vector_type(8))) short short8;

#define SCALE_Q 0.20412414523193154f   // 24^-0.5
#define LN_EPS 1e-5f

// ---- LDS layout (bytes) ----
#define RXN 200      // row stride in bf16 for xn, lq, lk (192 + 8 pad)
#define OFF_XN 0         // xn [64][RXN] bf16 (resident through QKV phase)
#define OFF_Q  25600     // lq [64][RXN] bf16, [t][h*24+d]; LN scratch aliases
#define OFF_K  51200     // lk [64][RXN] bf16
#define OFF_VW 76800     // 8 heads * 64 f32 : vw accum (QKV) -> per-head logits
#define LDS_BYTES 78848  // 77 KB -> 2 blocks/CU (157,696 <= 163,840)

__device__ __forceinline__ floatx4 mfma16(short8 a, short8 b, floatx4 c) {
  return __builtin_amdgcn_mfma_f32_16x16x32_bf16(a, b, c, 0, 0, 0);
}

// ---------------------------------------------------------------------------
// prep: pack w_qkv^T into per-fragment lane order (bf16) + wbar/bbar
// wfrag layout: [ntile j (36)][kstep s (6)][lane (64)][8 bf16]
//   element = w_qkv[32s + (lane>>4)*8 + i][16j + (lane&15)]
// ---------------------------------------------------------------------------
__global__ void prep_kernel(const float* __restrict__ w_qkv,
                            const float* __restrict__ w_proj,
                            const float* __restrict__ b_proj,
                            __hip_bfloat16* __restrict__ wfrag,
                            float* __restrict__ wbar) {
  int tid = blockIdx.x * 256 + threadIdx.x;
  if (tid < 36 * 6 * 64) {
    int j = tid / 384, rem = tid % 384, ksr = rem / 64, l = rem % 64;
    int n  = 16 * j + (l & 15);
    int k0 = 32 * ksr + (l >> 4) * 8;
#pragma unroll
    for (int i = 0; i < 8; ++i)
      wfrag[(size_t)tid * 8 + i] = __float2bfloat16(w_qkv[(k0 + i) * 576 + n]);
  }
  if (tid < 192) {
    float s = 0.f;
    for (int c = 0; c < 192; ++c) s += w_proj[tid * 192 + c];
    wbar[tid] = s * (1.f / 192.f);
  } else if (tid == 192) {
    float s = 0.f;
    for (int c = 0; c < 192; ++c) s += b_proj[c];
    wbar[192] = s * (1.f / 192.f);
  }
}

// ---------------------------------------------------------------------------
// main fused kernel: 512 blocks (bb = blk%8 -> XCD-stable image,
// wh = (blk>>3)&31, hseg = blk>>8 column half), 16 windows each.
// 512 threads = 8 waves. QKV: wave w owns row-tile mi=w&3, j-half jh=w>>2.
// Attention: wave w owns head w. Barriers/iter: A (LN scratch), B (xn),
// C (q/k/vw), D (logits).
// ---------------------------------------------------------------------------
__global__ __launch_bounds__(512, 2) void swin_kernel(
    const float* __restrict__ x,
    const float* __restrict__ gamma,
    const float* __restrict__ beta,
    const float* __restrict__ b_qkv,
    const __hip_bfloat16* __restrict__ wfrag,
    const float* __restrict__ wbar,
    float* __restrict__ out) {
  __shared__ __align__(16) char smem[LDS_BYTES];
  __hip_bfloat16* xn = (__hip_bfloat16*)(smem + OFF_XN);
  __hip_bfloat16* lq = (__hip_bfloat16*)(smem + OFF_Q);
  __hip_bfloat16* lk = (__hip_bfloat16*)(smem + OFF_K);
  float* vwf = (float*)(smem + OFF_VW);
  float2* scratch = (float2*)(smem + OFF_Q);   // alias of lq (LN phase only)

  const int tid = threadIdx.x;
  const int w   = tid >> 6;
  const int l   = tid & 63;
  const int l15 = l & 15;
  const int lg  = l >> 4;
  const int mi  = w & 3;               // QKV row-tile ownership
  const int jh  = w >> 2;              // QKV column-half ownership
  const floatx4 fzero = {0.f, 0.f, 0.f, 0.f};
  const short8 zero8 = {0, 0, 0, 0, 0, 0, 0, 0};

  const int p    = blockIdx.x;
  const int bb   = p & 7;              // image (== XCD under blockIdx%8 round-robin)
  const int wh   = (p >> 3) & 31;      // window row
  const int hseg = p >> 8;             // column half: ww = hseg*16 + it
  const int tr = l >> 3, tc = l & 7;   // lane <-> token (r,c) in 8x8 window
  const int c0 = w * 24;               // this wave's channel slice (LN)
  const float* xb = x + (size_t)bb * 192 * 65536 + (size_t)(wh * 8 + tr) * 256
                      + hseg * 128 + tc;

  float xr[24];
#pragma unroll
  for (int i = 0; i < 24; ++i) xr[i] = xb[(size_t)(c0 + i) * 65536];

#pragma unroll 1
  for (int it = 0; it < 16; ++it) {
    // ---------------- LayerNorm (lane = token, regs hold 24 channels) -------
    float s1 = 0.f, s2 = 0.f;
#pragma unroll
    for (int i = 0; i < 24; ++i) { s1 += xr[i]; s2 += xr[i] * xr[i]; }
    scratch[w * 64 + l] = make_float2(s1, s2);
    __syncthreads();                                           // (A)
    float ts = 0.f, tq = 0.f;
#pragma unroll
    for (int g = 0; g < 8; ++g) { float2 v = scratch[g * 64 + l]; ts += v.x; tq += v.y; }
    vwf[tid] = 0.f;   // reset vw accum for this window (fenced by A / B)
    const float mu   = ts * (1.f / 192.f);
    const float rstd = rsqrtf(tq * (1.f / 192.f) - mu * mu + LN_EPS);
    {
      short8 pk[3];
#pragma unroll
      for (int i = 0; i < 24; ++i) {
        float xv = (xr[i] - mu) * rstd * gamma[c0 + i] + beta[c0 + i];
        __hip_bfloat16 hb = __float2bfloat16(xv);
        short sv; __builtin_memcpy(&sv, &hb, 2);
        pk[i >> 3][i & 7] = sv;
      }
#pragma unroll
      for (int q2 = 0; q2 < 3; ++q2)          // b128 stores: conflict-free
        *(short8*)&xn[l * RXN + c0 + q2 * 8] = pk[q2];
    }
    __syncthreads();                                           // (B)

    // ---------------- QKV GEMM: xn(64x192) @ w_qkv(192x576) -----------------
    // Wave (mi, jh): A fragments for row-tile mi only (24 VGPRs), 18 j-tiles.
    short8 af[6];
#pragma unroll
    for (int ks = 0; ks < 6; ++ks)
      af[ks] = *(const short8*)&xn[(16 * mi + l15) * RXN + 32 * ks + lg * 8];

    auto gemm = [&](int j) -> floatx4 {
      floatx4 aa = fzero;
      const short8* bp = (const short8*)wfrag + (size_t)(j * 384 + l);
#pragma unroll
      for (int ks = 0; ks < 6; ++ks)
        aa = mfma16(af[ks], bp[ks * 64], aa);   // coalesced 1KB, L2-resident
      return aa;
    };
    auto kwrite = [&](int j, floatx4 aa) {
      const int cc = 16 * j + l15 - 192;
      const int hh = cc / 24, dd = cc - hh * 24;
      const float bias = b_qkv[16 * j + l15];
#pragma unroll
      for (int rg = 0; rg < 4; ++rg) {
        int t = 16 * mi + lg * 4 + rg;
        lk[t * RXN + hh * 24 + dd] = __float2bfloat16(aa[rg] + bias);
      }
    };

    if (jh == 0) {
#pragma unroll 2
      for (int j = 0; j < 12; ++j) {           // ---- Q (SCALE folded in) ----
        floatx4 aa = gemm(j);
        const int n = 16 * j + l15;
        const int hh = n / 24, dd = n - hh * 24;
        const float bias = b_qkv[n];
#pragma unroll
        for (int rg = 0; rg < 4; ++rg) {
          int t = 16 * mi + lg * 4 + rg;
          lq[t * RXN + hh * 24 + dd] = __float2bfloat16((aa[rg] + bias) * SCALE_Q);
        }
      }
#pragma unroll 2
      for (int j = 12; j < 18; ++j) kwrite(j, gemm(j));
    } else {
#pragma unroll 2
      for (int j = 18; j < 24; ++j) kwrite(j, gemm(j));
#pragma unroll 2
      for (int j = 24; j < 36; ++j) {          // ---- V: reduce straight to vw ----
        floatx4 aa = gemm(j);
        const int cc = 16 * j + l15 - 384;
        const int hh = cc / 24;                // 8-aligned spans stay in one head
        const float wbv = wbar[cc];
        const float bias = b_qkv[16 * j + l15];
        float part[4];
#pragma unroll
        for (int rg = 0; rg < 4; ++rg)
          part[rg] = (aa[rg] + bias) * wbv;
#pragma unroll
        for (int rg = 0; rg < 4; ++rg) {       // head-pure 8-lane reduction
          float t0 = part[rg];
          t0 += __shfl_xor(t0, 1);
          t0 += __shfl_xor(t0, 2);
          t0 += __shfl_xor(t0, 4);
          part[rg] = t0;
        }
        if ((l15 & 7) == 0)
#pragma unroll
          for (int rg = 0; rg < 4; ++rg) {
            int t = 16 * mi + lg * 4 + rg;
            atomicAdd(&vwf[hh * 64 + t], part[rg]);
          }
      }
    }
    __syncthreads();                                           // (C)

    // ---------------- attention: wave w = head w, per row-block i -----------
    {
      const int hh = w;
      short8 kf[4];
#pragma unroll
      for (int j2 = 0; j2 < 4; ++j2)
        kf[j2] = (lg < 3)
                   ? *(const short8*)&lk[(16 * j2 + l15) * RXN + hh * 24 + lg * 8]
                   : zero8;
      float vwv[4];                            // this head's vw vector slice
#pragma unroll
      for (int j2 = 0; j2 < 4; ++j2) vwv[j2] = vwf[hh * 64 + 16 * j2 + l15];

#pragma unroll
      for (int i = 0; i < 4; ++i) {
        short8 qf = (lg < 3)
                      ? *(const short8*)&lq[(16 * i + l15) * RXN + hh * 24 + lg * 8]
                      : zero8;
        floatx4 sc[4];
#pragma unroll
        for (int j2 = 0; j2 < 4; ++j2)
          sc[j2] = mfma16(qf, kf[j2], fzero);
        float num[4] = {0.f, 0.f, 0.f, 0.f};
        float den[4] = {0.f, 0.f, 0.f, 0.f};
#pragma unroll
        for (int j2 = 0; j2 < 4; ++j2)
#pragma unroll
          for (int rg = 0; rg < 4; ++rg) {
            float pv = exp2f(sc[j2][rg] * 1.44269504f);  // |s|<~40, fp32 safe
            den[rg] += pv;
            num[rg] = fmaf(pv, vwv[j2], num[rg]);
          }
#pragma unroll
        for (int m = 1; m < 16; m <<= 1)       // butterfly over l15 (in-group)
#pragma unroll
          for (int rg = 0; rg < 4; ++rg) {
            num[rg] += __shfl_xor(num[rg], m);
            den[rg] += __shfl_xor(den[rg], m);
          }
        // one unique lane per (i,rg) per lane-group stores the row's logit;
        // overwrites this wave's own (already-consumed) vw slice.
#pragma unroll
        for (int rg = 0; rg < 4; ++rg)
          if (l15 == i * 4 + rg)
            vwf[hh * 64 + 16 * i + lg * 4 + rg] = __fdividef(num[rg], den[rg]);
      }
    }
    __syncthreads();                                           // (D)

    // prefetch next window's x (live range overlaps only the epilogue; TLP
    // at 16 waves/CU covers the latency into next iteration's LN)
    if (it < 15) {
#pragma unroll
      for (int i = 0; i < 24; ++i)
        xr[i] = xb[(size_t)(c0 + i) * 65536 + (it + 1) * 8];
    }

    // ---------------- epilogue: sum 8 per-head logits -----------------------
    if (tid < 64) {
      float vL = wbar[192];
#pragma unroll
      for (int h8 = 0; h8 < 8; ++h8) vL += vwf[h8 * 64 + tid];
      out[(size_t)bb * 65536 + (size_t)(wh * 8 + (tid >> 3)) * 256
          + hseg * 128 + it * 8 + (tid & 7)] = 1.f / (1.f + __expf(-vL));
    }
  }
}

// ---------------------------------------------------------------------------
extern "C" void kernel_launch(void* const* d_in, const int* in_sizes, int n_in,
                              void* d_out, int out_size, void* d_ws, size_t ws_size,
                              hipStream_t stream) {
  const float* x      = (const float*)d_in[0];
  const float* gamma  = (const float*)d_in[1];
  const float* beta   = (const float*)d_in[2];
  const float* w_qkv  = (const float*)d_in[3];
  const float* b_qkv  = (const float*)d_in[4];
  const float* w_proj = (const float*)d_in[5];
  const float* b_proj = (const float*)d_in[6];
  float* out = (float*)d_out;

  __hip_bfloat16* wfrag = (__hip_bfloat16*)d_ws;          // 221184 B
  float* wbar = (float*)((char*)d_ws + 221184);           // 193 f32 (wbar + bbar)

  prep_kernel<<<54, 256, 0, stream>>>(w_qkv, w_proj, b_proj, wfrag, wbar);
  swin_kernel<<<512, 512, 0, stream>>>(x, gamma, beta, b_qkv, wfrag, wbar, out);
}

// Round 6
// 1192.217 us; speedup vs baseline: 1.0954x; 1.0954x over previous
//
#include <hip/hip_runtime.h>
#include <hip/hip_bf16.h>

// TransformerSpatialAttention on MI355X (gfx950)
// B=8, C=192, H=W=256, WS=8 -> 8192 windows x 64 tokens x 192 ch, NH=8, HD=24.
//
// Algebraic reduction (carried over): out = sigmoid(xa . wbar + bbar);
// V never stored, projection GEMM never run.
//
// Round-6: round 5 never ran (container failed twice = infra). Source
// re-audited for hang/fault modes (LDS bounds, barrier divergence, alias
// fencing) -- clean. Resubmitting unchanged for the occupancy diagnostic:
// LDS 53,248 B (lq aliases xn, +barrier B2) and arch demand ~100
// (af[2][6] mi2xjq split, 9 tiles/wave, B-dup 2x; log2e folded into Q
// scale; gamma/beta float4). launch_bounds(512,2) kept -- the only setting
// that doesn't trigger the 64-reg spill heuristic.
// If occupancy stays ~24% despite 53KB/105reg: gate is unified-file (AGPR)
// allocation -> next round forces AGPR-free codegen.

typedef __attribute__((ext_vector_type(4))) float floatx4;
typedef __attribute__((ext_vector_type(8))) short short8;

#define SCALE_QL2 0.29448889f   // 24^-0.5 * log2(e): S*log2e comes out of QK^T
#define LN_EPS 1e-5f

// ---- LDS layout (bytes) ----
#define RXN 200      // row stride in bf16 for xn / lq / lk (192 + 8 pad)
#define OFF_XN 0         // xn [64][RXN] bf16 ; lq aliases after B2
#define OFF_K  25600     // lk [64][RXN] bf16 ; LN scratch (4 KB) aliases (LN phase)
#define OFF_VW 51200     // 8 heads * 64 f32 : vw accum (QKV) -> per-head logits
#define LDS_BYTES 53248  // 52 KB -> 2 blocks/CU = 106,496 (proven region)

__device__ __forceinline__ floatx4 mfma16(short8 a, short8 b, floatx4 c) {
  return __builtin_amdgcn_mfma_f32_16x16x32_bf16(a, b, c, 0, 0, 0);
}

// ---------------------------------------------------------------------------
// prep: pack w_qkv^T into per-fragment lane order (bf16) + wbar/bbar
// wfrag layout: [ntile j (36)][kstep s (6)][lane (64)][8 bf16]
//   element = w_qkv[32s + (lane>>4)*8 + i][16j + (lane&15)]
// ---------------------------------------------------------------------------
__global__ void prep_kernel(const float* __restrict__ w_qkv,
                            const float* __restrict__ w_proj,
                            const float* __restrict__ b_proj,
                            __hip_bfloat16* __restrict__ wfrag,
                            float* __restrict__ wbar) {
  int tid = blockIdx.x * 256 + threadIdx.x;
  if (tid < 36 * 6 * 64) {
    int j = tid / 384, rem = tid % 384, ksr = rem / 64, l = rem % 64;
    int n  = 16 * j + (l & 15);
    int k0 = 32 * ksr + (l >> 4) * 8;
#pragma unroll
    for (int i = 0; i < 8; ++i)
      wfrag[(size_t)tid * 8 + i] = __float2bfloat16(w_qkv[(k0 + i) * 576 + n]);
  }
  if (tid < 192) {
    float s = 0.f;
    for (int c = 0; c < 192; ++c) s += w_proj[tid * 192 + c];
    wbar[tid] = s * (1.f / 192.f);
  } else if (tid == 192) {
    float s = 0.f;
    for (int c = 0; c < 192; ++c) s += b_proj[c];
    wbar[192] = s * (1.f / 192.f);
  }
}

// ---------------------------------------------------------------------------
// main fused kernel: 512 blocks (bb = blk%8 -> XCD-stable image,
// wh = (blk>>3)&31, hseg = blk>>8 column half), 16 windows each.
// 512 threads = 8 waves. QKV: wave w owns row-half mi2=w&1 (af[2][6]=48 regs)
// and j-quarter jq=w>>1 (9 tiles). Attention: wave w owns head w.
// Barriers/iter: A (LN scratch), B (xn), B2 (af cached; lq may clobber xn),
// C (q/k/vw), D (logits).
// ---------------------------------------------------------------------------
__global__ __launch_bounds__(512, 2) void swin_kernel(
    const float* __restrict__ x,
    const float* __restrict__ gamma,
    const float* __restrict__ beta,
    const float* __restrict__ b_qkv,
    const __hip_bfloat16* __restrict__ wfrag,
    const float* __restrict__ wbar,
    float* __restrict__ out) {
  __shared__ __align__(16) char smem[LDS_BYTES];
  __hip_bfloat16* xn = (__hip_bfloat16*)(smem + OFF_XN);
  __hip_bfloat16* lq = (__hip_bfloat16*)(smem + OFF_XN);  // alias (post-B2)
  __hip_bfloat16* lk = (__hip_bfloat16*)(smem + OFF_K);
  float* vwf = (float*)(smem + OFF_VW);
  float2* scratch = (float2*)(smem + OFF_K);              // alias of lk (LN phase)

  const int tid = threadIdx.x;
  const int w   = tid >> 6;
  const int l   = tid & 63;
  const int l15 = l & 15;
  const int lg  = l >> 4;
  const int mi2 = w & 1;               // QKV row-half ownership (rows 32*mi2..)
  const int jq  = w >> 1;              // QKV j-quarter ownership (9 tiles)
  const floatx4 fzero = {0.f, 0.f, 0.f, 0.f};
  const short8 zero8 = {0, 0, 0, 0, 0, 0, 0, 0};

  const int p    = blockIdx.x;
  const int bb   = p & 7;              // image (== XCD under blockIdx%8 round-robin)
  const int wh   = (p >> 3) & 31;      // window row
  const int hseg = p >> 8;             // column half: ww = hseg*16 + it
  const int tr = l >> 3, tc = l & 7;   // lane <-> token (r,c) in 8x8 window
  const int c0 = w * 24;               // this wave's channel slice (LN)
  const float* xb = x + (size_t)bb * 192 * 65536 + (size_t)(wh * 8 + tr) * 256
                      + hseg * 128 + tc;

  float xr[24];
#pragma unroll
  for (int i = 0; i < 24; ++i) xr[i] = xb[(size_t)(c0 + i) * 65536];

#pragma unroll 1
  for (int it = 0; it < 16; ++it) {
    // ---------------- LayerNorm (lane = token, regs hold 24 channels) -------
    float s1 = 0.f, s2 = 0.f;
#pragma unroll
    for (int i = 0; i < 24; ++i) { s1 += xr[i]; s2 += xr[i] * xr[i]; }
    scratch[w * 64 + l] = make_float2(s1, s2);
    __syncthreads();                                           // (A)
    float ts = 0.f, tq = 0.f;
#pragma unroll
    for (int g = 0; g < 8; ++g) { float2 v = scratch[g * 64 + l]; ts += v.x; tq += v.y; }
    vwf[tid] = 0.f;   // reset vw accum for this window (fenced by A / B)
    const float mu   = ts * (1.f / 192.f);
    const float rstd = rsqrtf(tq * (1.f / 192.f) - mu * mu + LN_EPS);
    {
      const float4* g4 = (const float4*)(gamma + c0);   // c0*4 % 16 == 0
      const float4* b4 = (const float4*)(beta + c0);
      short8 pk[3];
#pragma unroll
      for (int i4 = 0; i4 < 6; ++i4) {
        float4 gv = g4[i4], bv = b4[i4];
        float gg[4] = {gv.x, gv.y, gv.z, gv.w};
        float bbv[4] = {bv.x, bv.y, bv.z, bv.w};
#pragma unroll
        for (int q2 = 0; q2 < 4; ++q2) {
          int i = 4 * i4 + q2;
          float xv = (xr[i] - mu) * rstd * gg[q2] + bbv[q2];
          __hip_bfloat16 hb = __float2bfloat16(xv);
          short sv; __builtin_memcpy(&sv, &hb, 2);
          pk[i >> 3][i & 7] = sv;
        }
      }
#pragma unroll
      for (int q2 = 0; q2 < 3; ++q2)          // b128 stores: conflict-free
        *(short8*)&xn[l * RXN + c0 + q2 * 8] = pk[q2];
    }
    __syncthreads();                                           // (B)

    // A fragments for this wave's row-half (48 VGPRs); xn dies at B2
    short8 af[2][6];
#pragma unroll
    for (int m2 = 0; m2 < 2; ++m2)
#pragma unroll
      for (int ks = 0; ks < 6; ++ks)
        af[m2][ks] = *(const short8*)
            &xn[(32 * mi2 + 16 * m2 + l15) * RXN + 32 * ks + lg * 8];
    __syncthreads();                                           // (B2) lq writable

    // ---------------- QKV GEMM: xn(64x192) @ w_qkv(192x576) -----------------
#pragma unroll 1
    for (int j = jq * 9; j < jq * 9 + 9; ++j) {
      floatx4 aa[2] = {fzero, fzero};
      const short8* bp = (const short8*)wfrag + (size_t)(j * 384 + l);
#pragma unroll
      for (int ks = 0; ks < 6; ++ks) {
        short8 bf = bp[ks * 64];               // coalesced 1KB, L2-resident
        aa[0] = mfma16(af[0][ks], bf, aa[0]);
        aa[1] = mfma16(af[1][ks], bf, aa[1]);
      }
      const int n = 16 * j + l15;
      const float bias = b_qkv[n];
      if (j < 12) {                            // ---- Q (scale*log2e folded) --
        const int hh = n / 24, dd = n - hh * 24;
#pragma unroll
        for (int m2 = 0; m2 < 2; ++m2)
#pragma unroll
          for (int rg = 0; rg < 4; ++rg) {
            int t = 32 * mi2 + 16 * m2 + lg * 4 + rg;
            lq[t * RXN + hh * 24 + dd] =
                __float2bfloat16((aa[m2][rg] + bias) * SCALE_QL2);
          }
      } else if (j < 24) {                     // ---- K ----
        const int cc = n - 192;
        const int hh = cc / 24, dd = cc - hh * 24;
#pragma unroll
        for (int m2 = 0; m2 < 2; ++m2)
#pragma unroll
          for (int rg = 0; rg < 4; ++rg) {
            int t = 32 * mi2 + 16 * m2 + lg * 4 + rg;
            lk[t * RXN + hh * 24 + dd] = __float2bfloat16(aa[m2][rg] + bias);
          }
      } else {                                 // ---- V: reduce straight to vw ----
        const int cc = n - 384;
        const int hh = cc / 24;                // head boundaries 8-aligned in l15
        const float wbv = wbar[cc];
#pragma unroll
        for (int m2 = 0; m2 < 2; ++m2) {
          float part[4];
#pragma unroll
          for (int rg = 0; rg < 4; ++rg)
            part[rg] = (aa[m2][rg] + bias) * wbv;
#pragma unroll
          for (int rg = 0; rg < 4; ++rg) {     // head-pure 8-lane reduction
            float t0 = part[rg];
            t0 += __shfl_xor(t0, 1);
            t0 += __shfl_xor(t0, 2);
            t0 += __shfl_xor(t0, 4);
            part[rg] = t0;
          }
          if ((l15 & 7) == 0)
#pragma unroll
            for (int rg = 0; rg < 4; ++rg) {
              int t = 32 * mi2 + 16 * m2 + lg * 4 + rg;
              atomicAdd(&vwf[hh * 64 + t], part[rg]);
            }
        }
      }
    }
    __syncthreads();                                           // (C)

    // ---------------- attention: wave w = head w, per row-block i -----------
    {
      const int hh = w;
      short8 kf[4];
#pragma unroll
      for (int j2 = 0; j2 < 4; ++j2)
        kf[j2] = (lg < 3)
                   ? *(const short8*)&lk[(16 * j2 + l15) * RXN + hh * 24 + lg * 8]
                   : zero8;
      float vwv[4];                            // this head's vw vector slice
#pragma unroll
      for (int j2 = 0; j2 < 4; ++j2) vwv[j2] = vwf[hh * 64 + 16 * j2 + l15];

#pragma unroll
      for (int i = 0; i < 4; ++i) {
        short8 qf = (lg < 3)
                      ? *(const short8*)&lq[(16 * i + l15) * RXN + hh * 24 + lg * 8]
                      : zero8;
        floatx4 sc[4];
#pragma unroll
        for (int j2 = 0; j2 < 4; ++j2)
          sc[j2] = mfma16(qf, kf[j2], fzero);
        float num[4] = {0.f, 0.f, 0.f, 0.f};
        float den[4] = {0.f, 0.f, 0.f, 0.f};
#pragma unroll
        for (int j2 = 0; j2 < 4; ++j2)
#pragma unroll
          for (int rg = 0; rg < 4; ++rg) {
            float pv = exp2f(sc[j2][rg]);      // log2e pre-folded into Q
            den[rg] += pv;
            num[rg] = fmaf(pv, vwv[j2], num[rg]);
          }
#pragma unroll
        for (int m = 1; m < 16; m <<= 1)       // butterfly over l15 (in-group)
#pragma unroll
          for (int rg = 0; rg < 4; ++rg) {
            num[rg] += __shfl_xor(num[rg], m);
            den[rg] += __shfl_xor(den[rg], m);
          }
        // one unique lane per (i,rg) per lane-group stores the row's logit;
        // overwrites this wave's own (already-consumed) vw slice.
#pragma unroll
        for (int rg = 0; rg < 4; ++rg)
          if (l15 == i * 4 + rg)
            vwf[hh * 64 + 16 * i + lg * 4 + rg] = __fdividef(num[rg], den[rg]);
      }
    }
    __syncthreads();                                           // (D)

    // prefetch next window's x (xr dead during QKV/attention; live range is
    // epilogue -> next LN only; TLP covers the HBM latency)
    if (it < 15) {
#pragma unroll
      for (int i = 0; i < 24; ++i)
        xr[i] = xb[(size_t)(c0 + i) * 65536 + (it + 1) * 8];
    }

    // ---------------- epilogue: sum 8 per-head logits -----------------------
    if (tid < 64) {
      float vL = wbar[192];
#pragma unroll
      for (int h8 = 0; h8 < 8; ++h8) vL += vwf[h8 * 64 + tid];
      out[(size_t)bb * 65536 + (size_t)(wh * 8 + (tid >> 3)) * 256
          + hseg * 128 + it * 8 + (tid & 7)] = 1.f / (1.f + __expf(-vL));
    }
  }
}

// ---------------------------------------------------------------------------
extern "C" void kernel_launch(void* const* d_in, const int* in_sizes, int n_in,
                              void* d_out, int out_size, void* d_ws, size_t ws_size,
                              hipStream_t stream) {
  const float* x      = (const float*)d_in[0];
  const float* gamma  = (const float*)d_in[1];
  const float* beta   = (const float*)d_in[2];
  const float* w_qkv  = (const float*)d_in[3];
  const float* b_qkv  = (const float*)d_in[4];
  const float* w_proj = (const float*)d_in[5];
  const float* b_proj = (const float*)d_in[6];
  float* out = (float*)d_out;

  __hip_bfloat16* wfrag = (__hip_bfloat16*)d_ws;          // 221184 B
  float* wbar = (float*)((char*)d_ws + 221184);           // 193 f32 (wbar + bbar)

  prep_kernel<<<54, 256, 0, stream>>>(w_qkv, w_proj, b_proj, wfrag, wbar);
  swin_kernel<<<512, 512, 0, stream>>>(x, gamma, beta, b_qkv, wfrag, wbar, out);
}